// Round 1
// baseline (166.965 us; speedup 1.0000x reference)
//
#include <hip/hip_runtime.h>
#include <hip/hip_bf16.h>

typedef __attribute__((ext_vector_type(8))) __bf16 bf16x8;
typedef __attribute__((ext_vector_type(4))) float f32x4;

#define BATCH   1048576
#define DISTIL  128
#define CLASSES 64

// One wave computes a 16-row x 64-class output tile with 4x mfma_f32_16x16x32_bf16.
// A fragment (16x32): lane l holds z[row = l&15][k = (l>>4)*8 + j], j=0..7
// B fragment (32x16): lane l holds W[k = (l>>4)*8 + j][col = l&15]
// C/D fragment:       lane l, reg j -> C[row = (l>>4)*4 + j][col = l&15]   (m89-verified)
__global__ __launch_bounds__(256, 4) void linclass_kernel(
    const float* __restrict__ z, const float* __restrict__ W,
    const float* __restrict__ bias, float* __restrict__ out)
{
    const int lane = threadIdx.x & 63;
    const int wave = threadIdx.x >> 6;
    const int l15  = lane & 15;
    const int lhi  = lane >> 4;      // 0..3

    // ---- bias for this lane's columns: col = n*16 + l15 ----
    float bcol[4];
#pragma unroll
    for (int n = 0; n < 4; ++n) bcol[n] = bias[n * 16 + l15];

    // ---- W fragments, held in registers for the whole kernel ----
    // bw[n][kk][j] = W[kk*32 + lhi*8 + j][n*16 + l15]   (32 KB total; L2-hot broadcast)
    bf16x8 bw[4][4];
#pragma unroll
    for (int n = 0; n < 4; ++n) {
#pragma unroll
        for (int kk = 0; kk < 4; ++kk) {
            const int c     = n * 16 + l15;
            const int kbase = kk * 32 + lhi * 8;
#pragma unroll
            for (int j = 0; j < 8; ++j) {
                bw[n][kk][j] = (__bf16)W[(kbase + j) * CLASSES + c];
            }
        }
    }

    const long gwave  = (long)blockIdx.x * 4 + wave;
    const long nwaves = (long)gridDim.x * 4;
    const long ntiles = BATCH / 16;   // 65536, divides exactly

    for (long t = gwave; t < ntiles; t += nwaves) {
        const long rowbase = t * 16;

        f32x4 acc[4];
#pragma unroll
        for (int n = 0; n < 4; ++n) {
            acc[n][0] = bcol[n]; acc[n][1] = bcol[n];
            acc[n][2] = bcol[n]; acc[n][3] = bcol[n];
        }

        const float* zrow = z + (rowbase + l15) * (long)DISTIL;
#pragma unroll
        for (int kk = 0; kk < 4; ++kk) {
            const float* p = zrow + kk * 32 + lhi * 8;
            f32x4 x0 = *(const f32x4*)(p);
            f32x4 x1 = *(const f32x4*)(p + 4);
            bf16x8 a;
#pragma unroll
            for (int j = 0; j < 4; ++j) {
                a[j]     = (__bf16)x0[j];
                a[4 + j] = (__bf16)x1[j];
            }
#pragma unroll
            for (int n = 0; n < 4; ++n)
                acc[n] = __builtin_amdgcn_mfma_f32_16x16x32_bf16(a, bw[n][kk], acc[n], 0, 0, 0);
        }

        // store: row = rowbase + lhi*4 + j, col = n*16 + l15
        float* orow = out + (rowbase + lhi * 4) * (long)CLASSES + l15;
#pragma unroll
        for (int j = 0; j < 4; ++j) {
#pragma unroll
            for (int n = 0; n < 4; ++n) {
                orow[(long)j * CLASSES + n * 16] = acc[n][j];
            }
        }
    }
}

extern "C" void kernel_launch(void* const* d_in, const int* in_sizes, int n_in,
                              void* d_out, int out_size, void* d_ws, size_t ws_size,
                              hipStream_t stream) {
    const float* z    = (const float*)d_in[0];   // [1048576, 128]
    const float* W    = (const float*)d_in[1];   // [128, 64]
    const float* bias = (const float*)d_in[2];   // [64]
    float* out        = (float*)d_out;           // [1048576, 64]

    // 1024 blocks x 4 waves = 4096 waves = 16 waves/CU at <=128 VGPR (exactly resident);
    // grid-stride over 65536 tiles -> 16 tiles/wave, amortizes the W-fragment load.
    dim3 grid(1024), block(256);
    linclass_kernel<<<grid, block, 0, stream>>>(z, W, bias, out);
}